// Round 6
// baseline (497.910 us; speedup 1.0000x reference)
//
#include <hip/hip_runtime.h>

#define BIGF 1e20f
#define VF   1e10f

constexpr float SQ2 = 1.41421356237309515f;  // fp32 0x3FB504F3, == jnp.sqrt(2.0) in f32

// ---------------------------------------------------------------------------
// DPP helpers
// ---------------------------------------------------------------------------
__device__ __forceinline__ float dpp_left(float x)
{
    int o = __builtin_amdgcn_update_dpp(0x60AD78ECu /*1e20f*/, __float_as_int(x),
                                        0x138, 0xF, 0xF, false);   // WAVE_SHR1
    return __int_as_float(o);
}
__device__ __forceinline__ float dpp_right(float x)
{
    int o = __builtin_amdgcn_update_dpp(0x60AD78ECu /*1e20f*/, __float_as_int(x),
                                        0x130, 0xF, 0xF, false);   // WAVE_SHL1
    return __int_as_float(o);
}
template<int CTRL>
__device__ __forceinline__ float qdpp(float x)   // quad_perm xor patterns
{
    return __int_as_float(__builtin_amdgcn_update_dpp(0, __float_as_int(x),
                                                      CTRL, 0xF, 0xF, true));
}
__device__ __forceinline__ float fmed3(float a, float b, float c)
{
    return __builtin_amdgcn_fmed3f(a, b, c);
}

__device__ __forceinline__ void load_row8(const float* __restrict__ M, int r, int c0, float v[8])
{
    const float4* q = (const float4*)(M + ((long)r << 9) + c0);
    float4 a = q[0], b = q[1];
    v[0] = a.x; v[1] = a.y; v[2] = a.z; v[3] = a.w;
    v[4] = b.x; v[5] = b.y; v[6] = b.z; v[7] = b.w;
}

// 3pt chamfer step: nv <- min(cur, p+1, min(neighbors)+SQ2)  (8 cols/lane)
__device__ __forceinline__ void step8(const float cur[8], const float p[8], float nv[8])
{
    float left  = dpp_left(p[7]);
    float right = dpp_right(p[0]);
    #pragma unroll
    for (int j = 0; j < 8; ++j) {
        float l  = (j == 0) ? left  : p[j - 1];
        float rr = (j == 7) ? right : p[j + 1];
        nv[j] = fminf(fminf(cur[j], p[j] + 1.0f), fminf(l, rr) + SQ2);
    }
}

// 3 and 4 cols/lane variants for trapezoid chunks. Out-of-chunk neighbors
// come in as 1e20 via DPP bound value (safe: detour monotonicity).
__device__ __forceinline__ void step3(const float cur[3], const float p[3], float nv[3])
{
    float left  = dpp_left(p[2]);
    float right = dpp_right(p[0]);
    nv[0] = fminf(fminf(cur[0], p[0] + 1.0f), fminf(left, p[1]) + SQ2);
    nv[1] = fminf(fminf(cur[1], p[1] + 1.0f), fminf(p[0], p[2]) + SQ2);
    nv[2] = fminf(fminf(cur[2], p[2] + 1.0f), fminf(p[1], right) + SQ2);
}
__device__ __forceinline__ void step4(const float cur[4], const float p[4], float nv[4])
{
    float left  = dpp_left(p[3]);
    float right = dpp_right(p[0]);
    nv[0] = fminf(fminf(cur[0], p[0] + 1.0f), fminf(left, p[1]) + SQ2);
    nv[1] = fminf(fminf(cur[1], p[1] + 1.0f), fminf(p[0], p[2]) + SQ2);
    nv[2] = fminf(fminf(cur[2], p[2] + 1.0f), fminf(p[1], p[3]) + SQ2);
    nv[3] = fminf(fminf(cur[3], p[3] + 1.0f), fminf(p[2], right) + SQ2);
}

// ---------------------------------------------------------------------------
// K1: binarize + channel max + dist init + scalar inits
// ---------------------------------------------------------------------------
__global__ __launch_bounds__(256) void k_init(const float* __restrict__ pred,
                                              const float* __restrict__ tgt,
                                              float* __restrict__ bufA,
                                              float* __restrict__ acc,
                                              unsigned* __restrict__ count,
                                              float* __restrict__ minmax)
{
    if (blockIdx.x == 0 && threadIdx.x == 0) { *acc = 0.0f; *count = 0u; }
    if (blockIdx.x == 0 && threadIdx.x < 64)
        minmax[threadIdx.x] = (threadIdx.x & 1) ? 0.0f : BIGF;

    int r = blockIdx.x & 7;
    int k = blockIdx.x >> 3;
    int b = r + 8 * (k >> 10);
    int pix = (k & 1023) * 256 + threadIdx.x;
    long base = (long)b * 3 * 262144 + pix;

    float p0 = pred[base], p1 = pred[base + 262144], p2 = pred[base + 2 * 262144];
    bool fgP = ((p0 + 1.0f) * 0.5f >= 0.7f) ||
               ((p1 + 1.0f) * 0.5f >= 0.7f) ||
               ((p2 + 1.0f) * 0.5f >= 0.7f);

    float t0 = tgt[base], t1 = tgt[base + 262144], t2 = tgt[base + 2 * 262144];
    float mt = fmaxf(fmaxf(t0, t1), t2);

    bufA[(long)b * 262144 + pix]        = fgP ? 0.0f : VF;
    bufA[(long)(16 + b) * 262144 + pix] = VF * (1.0f - mt);
}

// ---------------------------------------------------------------------------
// K_p1d: phase-1 down (R1-proven full-band version). 512 WGs x 64,
// 8-deep ring (7 rows in flight).
// ---------------------------------------------------------------------------
__global__ __launch_bounds__(64) void k_p1d(const float* __restrict__ X0,
                                            float* __restrict__ Cb)
{
    int bi = blockIdx.x, m = bi >> 4, w = bi & 15;
    const float* X = X0 + ((long)m << 18);
    int c0 = (int)threadIdx.x << 3, a = w << 5;
    float p[8]; load_row8(X, a, c0, p);
    float buf[8][8];
    #pragma unroll
    for (int k = 1; k <= 7; ++k) load_row8(X, a + k, c0, buf[k & 7]);
    #pragma unroll
    for (int i = 1; i < 32; ++i) {
        if (i + 7 < 32) load_row8(X, a + i + 7, c0, buf[(i + 7) & 7]);
        float nv[8]; step8(buf[i & 7], p, nv);
        #pragma unroll
        for (int j = 0; j < 8; ++j) p[j] = nv[j];
    }
    float4* o = (float4*)(Cb + m * 8192 + w * 512 + c0);
    o[0] = make_float4(p[0], p[1], p[2], p[3]);
    o[1] = make_float4(p[4], p[5], p[6], p[7]);
}

// ---------------------------------------------------------------------------
// combine: bwp[wdst] = min(bwp[wdst], cone32(bwp[wsrc]))  (verified exact)
// ---------------------------------------------------------------------------
__device__ __forceinline__ void combine(float* __restrict__ bwp, float* __restrict__ part,
                                        int wdst, int wsrc, int t, int wave, int lane,
                                        const float wreg[8])
{
    const float* bs = bwp + wsrc * 576;
    if (wave <= 8) {
        int base = lane * 8 + 8 * wave;
        float W[16];
        float4 W0 = *(const float4*)(bs + base);
        float4 W1 = *(const float4*)(bs + base + 4);
        W[0]=W0.x; W[1]=W0.y; W[2]=W0.z; W[3]=W0.w;
        W[4]=W1.x; W[5]=W1.y; W[6]=W1.z; W[7]=W1.w;
        float acc[8];
        if (wave < 8) {
            float4 W2 = *(const float4*)(bs + base + 8);
            float4 W3 = *(const float4*)(bs + base + 12);
            W[8]=W2.x; W[9]=W2.y; W[10]=W2.z; W[11]=W2.w;
            W[12]=W3.x; W[13]=W3.y; W[14]=W3.z; W[15]=W3.w;
            #pragma unroll
            for (int j = 0; j < 8; ++j) acc[j] = W[j] + wreg[0];
            #pragma unroll
            for (int dt = 1; dt < 8; ++dt)
                #pragma unroll
                for (int j = 0; j < 8; ++j)
                    acc[j] = fminf(acc[j], W[j + dt] + wreg[dt]);
        } else {
            #pragma unroll
            for (int j = 0; j < 8; ++j) acc[j] = W[j] + wreg[0];
        }
        float4* pp = (float4*)(part + wave * 512 + lane * 8);
        pp[0] = make_float4(acc[0], acc[1], acc[2], acc[3]);
        pp[1] = make_float4(acc[4], acc[5], acc[6], acc[7]);
    }
    __syncthreads();
    if (t < 512) {
        float r = bwp[wdst * 576 + 32 + t];
        #pragma unroll
        for (int p2 = 0; p2 < 9; ++p2) r = fminf(r, part[p2 * 512 + t]);
        bwp[wdst * 576 + 32 + t] = r;
    }
    __syncthreads();
}

// ---------------------------------------------------------------------------
// K_comb: 15 serial combines over Cb (in place). dir=+1 down, -1 up. 32 WGs.
// ---------------------------------------------------------------------------
__global__ __launch_bounds__(1024) void k_comb(float* __restrict__ Cb, int dir)
{
    __shared__ __align__(16) float bwp[16 * 576];
    __shared__ __align__(16) float part[9 * 512];
    __shared__ float wgt[72];
    int m = blockIdx.x, t = threadIdx.x, wave = t >> 6, lane = t & 63, c0 = lane << 3;
    float* Cm = Cb + m * 8192;

    bwp[wave * 576 + ((lane < 32) ? lane : lane + 512)] = BIGF;
    *(float4*)(bwp + wave * 576 + 32 + c0)     = *(const float4*)(Cm + wave * 512 + c0);
    *(float4*)(bwp + wave * 576 + 32 + c0 + 4) = *(const float4*)(Cm + wave * 512 + c0 + 4);
    if (t < 65) { int d = t - 32; int ad = d < 0 ? -d : d; wgt[t] = ad * SQ2 + (float)(32 - ad); }
    __syncthreads();
    float wreg[8];
    #pragma unroll
    for (int dt = 0; dt < 8; ++dt) wreg[dt] = BIGF;
    if (wave < 8) {
        #pragma unroll
        for (int dt = 0; dt < 8; ++dt) wreg[dt] = wgt[wave * 8 + dt];
    } else if (wave == 8) wreg[0] = wgt[64];

    #pragma unroll 1
    for (int i = 0; i < 15; ++i) {
        int w2 = (dir > 0) ? (1 + i) : (14 - i);
        combine(bwp, part, w2, w2 - dir, t, wave, lane, wreg);
    }
    *(float4*)(Cm + wave * 512 + c0)     = *(const float4*)(bwp + wave * 576 + 32 + c0);
    *(float4*)(Cm + wave * 512 + c0 + 4) = *(const float4*)(bwp + wave * 576 + 32 + c0 + 4);
}

// ---------------------------------------------------------------------------
// K_p3d1u: seeded down (write Y owned) + fused band-local up from LDS stash.
// Trapezoid chunks: 256 cols loaded (4/lane float4), owned 128, 64 halo each
// side (down 32 + up 32). Stash: 32 rows x 192 cols = 24 KB. Single wave per
// WG -> no barriers. 2048 WGs.
// ---------------------------------------------------------------------------
__global__ __launch_bounds__(64) void k_p3d1u(const float* __restrict__ X0,
                                              float* __restrict__ Y0,
                                              const float* __restrict__ Cb,
                                              float* __restrict__ Db)
{
    __shared__ __align__(16) float stash[32 * 192];
    int bi = blockIdx.x;
    int u = bi & 3, w = (bi >> 2) & 15, m = bi >> 6;
    const float* X = X0 + ((long)m << 18);
    float* Y = Y0 + ((long)m << 18);
    const int ln = threadIdx.x;
    const int a = w << 5;
    const int c4 = (u << 7) - 64 + (ln << 2);     // elem0 col, 4-aligned; image
    const bool inb = (unsigned)c4 < 512u;         // edges at 0/512 -> whole f4
    const bool own4 = (ln >= 16) && (ln < 48);    // c4 in [128u, 128u+128)
    const bool st4  = (ln >= 8)  && (ln < 56);    // stash col in [0,192)
    const int sidx = (ln << 2) - 32;

    float p[4], buf[8][4];
    if (w) {
        if (inb) {
            float4 s = *(const float4*)(Cb + m * 8192 + (w - 1) * 512 + c4);
            p[0]=s.x; p[1]=s.y; p[2]=s.z; p[3]=s.w;
        } else { p[0]=p[1]=p[2]=p[3]=BIGF; }
    } else { p[0]=p[1]=p[2]=p[3]=BIGF; }

    #pragma unroll
    for (int k = 0; k < 7; ++k) {
        if (inb) {
            float4 v = *(const float4*)(X + ((long)(a + k) << 9) + c4);
            buf[k][0]=v.x; buf[k][1]=v.y; buf[k][2]=v.z; buf[k][3]=v.w;
        } else { buf[k][0]=buf[k][1]=buf[k][2]=buf[k][3]=BIGF; }
    }
    #pragma unroll
    for (int i = 0; i < 32; ++i) {
        if (i + 7 < 32) {
            int s = (i + 7) & 7;
            if (inb) {
                float4 v = *(const float4*)(X + ((long)(a + i + 7) << 9) + c4);
                buf[s][0]=v.x; buf[s][1]=v.y; buf[s][2]=v.z; buf[s][3]=v.w;
            } else { buf[s][0]=buf[s][1]=buf[s][2]=buf[s][3]=BIGF; }
        }
        float nv[4]; step4(buf[i & 7], p, nv);
        if (own4)
            *(float4*)(Y + ((long)(a + i) << 9) + c4) = make_float4(nv[0], nv[1], nv[2], nv[3]);
        if (st4)
            *(float4*)(stash + i * 192 + sidx) = make_float4(nv[0], nv[1], nv[2], nv[3]);
        p[0]=nv[0]; p[1]=nv[1]; p[2]=nv[2]; p[3]=nv[3];
    }

    // band-local up sweep on stash, 3-col/lane remap over stash cols [0,192)
    const int t3 = ln * 3;
    float q[3];
    q[0] = stash[31 * 192 + t3];
    q[1] = stash[31 * 192 + t3 + 1];
    q[2] = stash[31 * 192 + t3 + 2];
    #pragma unroll
    for (int i = 1; i < 32; ++i) {
        float cur[3];
        cur[0] = stash[(31 - i) * 192 + t3];
        cur[1] = stash[(31 - i) * 192 + t3 + 1];
        cur[2] = stash[(31 - i) * 192 + t3 + 2];
        float nv[3]; step3(cur, q, nv);
        q[0]=nv[0]; q[1]=nv[1]; q[2]=nv[2];
    }
    float* Drow = Db + m * 8192 + w * 512;
    #pragma unroll
    for (int e = 0; e < 3; ++e) {
        int t = t3 + e;                            // stash col; owned = [32,160)
        if (t >= 32 && t < 160) Drow[(u << 7) + t - 32] = q[e];
    }
}

// ---------------------------------------------------------------------------
// K_p3u: phase-3 up + fused TRANSPOSED write + minmax. Trapezoid chunks:
// 192 cols (3/lane), owned 128. Tile 16 x 132. 2048 WGs x 64. No barriers.
// ---------------------------------------------------------------------------
__device__ __forceinline__ void half_out3(const float* tile, float* __restrict__ Xo,
                                          int cbase, int a2, int ln)
{
    int g = ln >> 2, j = (ln & 3) << 2;
    #pragma unroll
    for (int it = 0; it < 8; ++it) {
        int c = (it << 4) + g;
        float4 v = make_float4(tile[(j + 0) * 132 + c], tile[(j + 1) * 132 + c],
                               tile[(j + 2) * 132 + c], tile[(j + 3) * 132 + c]);
        *(float4*)(Xo + (long)(cbase + c) * 512 + a2 + j) = v;
    }
}

__global__ __launch_bounds__(64) void k_p3u(const float* __restrict__ Y0,
                                            float* __restrict__ Xo0,
                                            const float* __restrict__ Db,
                                            float* __restrict__ minmax,
                                            int final_pass)
{
    __shared__ __align__(16) float tile[16 * 132];
    int bi = blockIdx.x;
    int u = bi & 3, w = (bi >> 2) & 15, m = bi >> 6;
    const float* Y = Y0 + ((long)m << 18);
    float* Xo = Xo0 + ((long)m << 18);
    const int ln = threadIdx.x;
    const int a = w << 5;
    const int cb = (u << 7) - 32 + ln * 3;
    bool ok[3], own[3]; int oc[3];
    #pragma unroll
    for (int e = 0; e < 3; ++e) {
        int c = cb + e;
        ok[e]  = (unsigned)c < 512u;
        oc[e]  = c - (u << 7);
        own[e] = (oc[e] >= 0) && (oc[e] < 128);
    }

    float p[3], buf[8][3];
    if (w < 15) {
        const float* S = Db + m * 8192 + (w + 1) * 512;
        p[0] = ok[0] ? S[cb    ] : BIGF;
        p[1] = ok[1] ? S[cb + 1] : BIGF;
        p[2] = ok[2] ? S[cb + 2] : BIGF;
    } else { p[0]=p[1]=p[2]=BIGF; }

    #pragma unroll
    for (int k = 0; k < 7; ++k) {
        const float* Yr = Y + ((long)(a + 31 - k) << 9);
        buf[k][0] = ok[0] ? Yr[cb    ] : BIGF;
        buf[k][1] = ok[1] ? Yr[cb + 1] : BIGF;
        buf[k][2] = ok[2] ? Yr[cb + 2] : BIGF;
    }

    float mn = BIGF, mx = -BIGF;
    #pragma unroll
    for (int i = 0; i < 16; ++i) {                // rows a+31..a+16 -> tile 15..0
        {
            const float* Yr = Y + ((long)(a + 31 - (i + 7)) << 9);
            buf[(i + 7) & 7][0] = ok[0] ? Yr[cb    ] : BIGF;
            buf[(i + 7) & 7][1] = ok[1] ? Yr[cb + 1] : BIGF;
            buf[(i + 7) & 7][2] = ok[2] ? Yr[cb + 2] : BIGF;
        }
        float nv[3]; step3(buf[i & 7], p, nv);
        #pragma unroll
        for (int e = 0; e < 3; ++e)
            if (own[e]) {
                tile[(15 - i) * 132 + oc[e]] = nv[e];
                mn = fminf(mn, nv[e]); mx = fmaxf(mx, nv[e]);
            }
        p[0]=nv[0]; p[1]=nv[1]; p[2]=nv[2];
    }
    half_out3(tile, Xo, u << 7, a + 16, ln);
    #pragma unroll
    for (int i = 16; i < 32; ++i) {               // rows a+15..a -> tile 15..0
        if (i + 7 < 32) {
            const float* Yr = Y + ((long)(a + 31 - (i + 7)) << 9);
            buf[(i + 7) & 7][0] = ok[0] ? Yr[cb    ] : BIGF;
            buf[(i + 7) & 7][1] = ok[1] ? Yr[cb + 1] : BIGF;
            buf[(i + 7) & 7][2] = ok[2] ? Yr[cb + 2] : BIGF;
        }
        float nv[3]; step3(buf[i & 7], p, nv);
        #pragma unroll
        for (int e = 0; e < 3; ++e)
            if (own[e]) {
                tile[(31 - i) * 132 + oc[e]] = nv[e];
                mn = fminf(mn, nv[e]); mx = fmaxf(mx, nv[e]);
            }
        p[0]=nv[0]; p[1]=nv[1]; p[2]=nv[2];
    }
    half_out3(tile, Xo, u << 7, a, ln);

    if (final_pass) {
        for (int o = 32; o > 0; o >>= 1) {
            mn = fminf(mn, __shfl_down(mn, o));
            mx = fmaxf(mx, __shfl_down(mx, o));
        }
        if (ln == 0) {
            atomicMin((int*)(minmax + 2 * m),     __float_as_int(mn));
            atomicMax((int*)(minmax + 2 * m + 1), __float_as_int(mx));
        }
    }
}

// ---------------------------------------------------------------------------
// K_loss: NORMALIZED bitonic sort (all comparators min-low) with med3 trick.
// lstage LDS slots XOR-half-swizzled (verified: conflicts 2.36M -> 786K).
// ---------------------------------------------------------------------------
__device__ __forceinline__ void cex(float& lo, float& hi)
{
    float l = fminf(lo, hi);
    hi = fmaxf(lo, hi);
    lo = l;
}
__device__ __forceinline__ void merge8asc(float v[8])
{
    cex(v[0],v[4]); cex(v[1],v[5]); cex(v[2],v[6]); cex(v[3],v[7]);
    cex(v[0],v[2]); cex(v[1],v[3]); cex(v[4],v[6]); cex(v[5],v[7]);
    cex(v[0],v[1]); cex(v[2],v[3]); cex(v[4],v[5]); cex(v[6],v[7]);
}
__device__ __forceinline__ void sort8asc(float v[8])
{
    cex(v[0],v[1]); cex(v[2],v[3]); cex(v[4],v[5]); cex(v[6],v[7]);   // k=2
    cex(v[0],v[3]); cex(v[1],v[2]); cex(v[4],v[7]); cex(v[5],v[6]);   // k=4 rev
    cex(v[0],v[1]); cex(v[2],v[3]); cex(v[4],v[5]); cex(v[6],v[7]);   // k=4 j=1
    cex(v[0],v[7]); cex(v[1],v[6]); cex(v[2],v[5]); cex(v[3],v[4]);   // k=8 rev
    cex(v[0],v[2]); cex(v[1],v[3]); cex(v[4],v[6]); cex(v[5],v[7]);   // j=2
    cex(v[0],v[1]); cex(v[2],v[3]); cex(v[4],v[5]); cex(v[6],v[7]);   // j=1
}
__device__ __forceinline__ void xshfl(float v[8], int j8, float sel)
{
    #pragma unroll
    for (int e = 0; e < 8; ++e) {
        float o = __shfl_xor(v[e], j8);
        v[e] = fmed3(v[e], o, sel);
    }
}
template<int CTRL>
__device__ __forceinline__ void xdpp(float v[8], float sel)
{
    #pragma unroll
    for (int e = 0; e < 8; ++e) {
        float o = qdpp<CTRL>(v[e]);
        v[e] = fmed3(v[e], o, sel);
    }
}
__device__ __forceinline__ void rshfl(float v[8], int tmask, float sel)
{
    float o[8];
    #pragma unroll
    for (int e = 0; e < 8; ++e) o[e] = __shfl_xor(v[7 - e], tmask);
    #pragma unroll
    for (int e = 0; e < 8; ++e) v[e] = fmed3(v[e], o[e], sel);
}
template<int CTRL>
__device__ __forceinline__ void rdpp(float v[8], float sel)
{
    float o[8];
    #pragma unroll
    for (int e = 0; e < 8; ++e) o[e] = qdpp<CTRL>(v[7 - e]);
    #pragma unroll
    for (int e = 0; e < 8; ++e) v[e] = fmed3(v[e], o[e], sel);
}
__device__ __forceinline__ void lstage(float p[8], float q[8], int tmask, float sel, bool rev,
                                       float* sp, float* st, int t)
{
    __syncthreads();
    int sw = (t >> 2) & 1;                 // half-swap swizzle bit
    int o0 = t * 8 + sw * 4;
    int o1 = t * 8 + (sw ^ 1) * 4;
    *(float4*)(sp + o0) = make_float4(p[0], p[1], p[2], p[3]);
    *(float4*)(sp + o1) = make_float4(p[4], p[5], p[6], p[7]);
    *(float4*)(st + o0) = make_float4(q[0], q[1], q[2], q[3]);
    *(float4*)(st + o1) = make_float4(q[4], q[5], q[6], q[7]);
    __syncthreads();
    int pt = t ^ tmask;
    int psw = (pt >> 2) & 1;
    int q0 = pt * 8 + psw * 4;
    int q1 = pt * 8 + (psw ^ 1) * 4;
    float4 a = *(const float4*)(sp + q0), bb = *(const float4*)(sp + q1);
    float4 c = *(const float4*)(st + q0), d = *(const float4*)(st + q1);
    float op[8] = {a.x,a.y,a.z,a.w,bb.x,bb.y,bb.z,bb.w};
    float oq[8] = {c.x,c.y,c.z,c.w,d.x,d.y,d.z,d.w};
    if (rev) {
        #pragma unroll
        for (int e = 0; e < 8; ++e) {
            p[e] = fmed3(p[e], op[7 - e], sel);
            q[e] = fmed3(q[e], oq[7 - e], sel);
        }
    } else {
        #pragma unroll
        for (int e = 0; e < 8; ++e) {
            p[e] = fmed3(p[e], op[e], sel);
            q[e] = fmed3(q[e], oq[e], sel);
        }
    }
}

__global__ __launch_bounds__(512) void k_loss(const float* __restrict__ bufB,
                                              const float* __restrict__ minmax,
                                              float* __restrict__ acc,
                                              unsigned* __restrict__ count,
                                              float* __restrict__ out)
{
    __shared__ float sp[4096];
    __shared__ float st[4096];
    __shared__ float rs[8];

    int t = threadIdx.x;
    int r = blockIdx.x & 7;
    int k = blockIdx.x >> 3;
    int b = r + 8 * (k >> 6);
    int w = k & 63;
    int wi = w >> 3, wj = w & 7;

    int i0 = t << 3;
    int y = wi * 64 + (i0 >> 6);
    int x = wj * 64 + (i0 & 63);

    float mnP = minmax[2 * b],        mxP = minmax[2 * b + 1];
    float mnT = minmax[2 * (16 + b)], mxT = minmax[2 * (16 + b) + 1];
    float sclP = 1.0f / (mxP - mnP + 1e-6f);
    float sclT = 1.0f / (mxT - mnT + 1e-6f);

    float p[8], q[8];
    {
        const float4* P4 = (const float4*)(bufB + (long)b * 262144 + y * 512 + x);
        const float4* T4 = (const float4*)(bufB + (long)(16 + b) * 262144 + y * 512 + x);
        float4 a = P4[0], bb = P4[1], c = T4[0], d = T4[1];
        p[0]=a.x; p[1]=a.y; p[2]=a.z; p[3]=a.w; p[4]=bb.x; p[5]=bb.y; p[6]=bb.z; p[7]=bb.w;
        q[0]=c.x; q[1]=c.y; q[2]=c.z; q[3]=c.w; q[4]=d.x;  q[5]=d.y;  q[6]=d.z;  q[7]=d.w;
        #pragma unroll
        for (int e = 0; e < 8; ++e) {
            p[e] = (p[e] - mnP) * sclP;
            q[e] = (q[e] - mnT) * sclT;
        }
    }

    const float INFP = __builtin_inff();
    sort8asc(p); sort8asc(q);

    #pragma unroll 1
    for (int kk = 16; kk <= 4096; kk <<= 1) {
        int tmask = (kk - 1) >> 3;
        float sel = ((t & (kk >> 4)) == 0) ? -INFP : INFP;
        if (kk == 16)        { rdpp<0xB1>(p, sel); rdpp<0xB1>(q, sel); }
        else if (kk == 32)   { rdpp<0x1B>(p, sel); rdpp<0x1B>(q, sel); }
        else if (tmask < 64) { rshfl(p, tmask, sel); rshfl(q, tmask, sel); }
        else                 lstage(p, q, tmask, sel, true, sp, st, t);

        #pragma unroll 1
        for (int j = kk >> 2; j >= 8; j >>= 1) {
            int j8 = j >> 3;
            float s2 = ((t & j8) == 0) ? -INFP : INFP;
            if (j8 == 1)      { xdpp<0xB1>(p, s2); xdpp<0xB1>(q, s2); }
            else if (j8 == 2) { xdpp<0x4E>(p, s2); xdpp<0x4E>(q, s2); }
            else if (j8 < 64) { xshfl(p, j8, s2); xshfl(q, j8, s2); }
            else              lstage(p, q, j8, s2, false, sp, st, t);
        }
        merge8asc(p); merge8asc(q);
    }

    float s = 0.0f;
    #pragma unroll
    for (int e = 0; e < 8; ++e) { float d = p[e] - q[e]; s += d * d; }
    for (int o = 32; o > 0; o >>= 1) s += __shfl_down(s, o);
    if ((t & 63) == 0) rs[t >> 6] = s;
    __syncthreads();
    if (t == 0) {
        float tot = 0.0f;
        #pragma unroll
        for (int i = 0; i < 8; ++i) tot += rs[i];
        atomicAdd(acc, tot);
        __threadfence();
        unsigned done = atomicAdd(count, 1u);
        if (done == 1023u) {
            float total = atomicAdd(acc, 0.0f);
            float mean = total * (1.0f / 4194304.0f);
            out[0] = mean * 0.005f;
            out[1] = mean;
        }
    }
}

extern "C" void kernel_launch(void* const* d_in, const int* in_sizes, int n_in,
                              void* d_out, int out_size, void* d_ws, size_t ws_size,
                              hipStream_t stream)
{
    const float* pred = (const float*)d_in[0];
    const float* tgt  = (const float*)d_in[1];
    float* out = (float*)d_out;

    char* ws = (char*)d_ws;
    float* bufA     = (float*)ws;                       // 32 MB
    float* bufB     = (float*)(ws + (32ull << 20));     // 32 MB (Y intermediate)
    float* Cb       = (float*)(ws + (64ull << 20));     // 1 MB boundary rows (down)
    float* Db       = (float*)(ws + (65ull << 20));     // 1 MB boundary rows (up)
    float* minmax   = (float*)(ws + (66ull << 20));     // 64 floats
    float* acc      = minmax + 64;
    unsigned* count = (unsigned*)(acc + 1);

    k_init<<<16 * 1024, 256, 0, stream>>>(pred, tgt, bufA, acc, count, minmax);

    for (int s = 0; s < 4; ++s) {
        k_p1d  <<< 512,   64, 0, stream>>>(bufA, Cb);
        k_comb <<<  32, 1024, 0, stream>>>(Cb, +1);
        k_p3d1u<<<2048,   64, 0, stream>>>(bufA, bufB, Cb, Db);
        k_comb <<<  32, 1024, 0, stream>>>(Db, -1);
        k_p3u  <<<2048,   64, 0, stream>>>(bufB, bufA, Db, minmax, s == 3 ? 1 : 0);
    }

    k_loss<<<1024, 512, 0, stream>>>(bufA, minmax, acc, count, out);
}

// Round 7
// 478.809 us; speedup vs baseline: 1.0399x; 1.0399x over previous
//
#include <hip/hip_runtime.h>

#define BIGF 1e20f
#define VF   1e10f

constexpr float SQ2 = 1.41421356237309515f;  // fp32 0x3FB504F3, == jnp.sqrt(2.0) in f32

// ---------------------------------------------------------------------------
// DPP helpers
// ---------------------------------------------------------------------------
__device__ __forceinline__ float dpp_left(float x)
{
    int o = __builtin_amdgcn_update_dpp(0x60AD78ECu /*1e20f*/, __float_as_int(x),
                                        0x138, 0xF, 0xF, false);   // WAVE_SHR1
    return __int_as_float(o);
}
__device__ __forceinline__ float dpp_right(float x)
{
    int o = __builtin_amdgcn_update_dpp(0x60AD78ECu /*1e20f*/, __float_as_int(x),
                                        0x130, 0xF, 0xF, false);   // WAVE_SHL1
    return __int_as_float(o);
}
template<int CTRL>
__device__ __forceinline__ float qdpp(float x)   // quad_perm xor patterns
{
    return __int_as_float(__builtin_amdgcn_update_dpp(0, __float_as_int(x),
                                                      CTRL, 0xF, 0xF, true));
}
__device__ __forceinline__ float fmed3(float a, float b, float c)
{
    return __builtin_amdgcn_fmed3f(a, b, c);
}

__device__ __forceinline__ void load_row8(const float* __restrict__ M, int r, int c0, float v[8])
{
    const float4* q = (const float4*)(M + ((long)r << 9) + c0);
    float4 a = q[0], b = q[1];
    v[0] = a.x; v[1] = a.y; v[2] = a.z; v[3] = a.w;
    v[4] = b.x; v[5] = b.y; v[6] = b.z; v[7] = b.w;
}
__device__ __forceinline__ void store_row8(float* __restrict__ M, int r, int c0, const float v[8])
{
    float4* q = (float4*)(M + ((long)r << 9) + c0);
    q[0] = make_float4(v[0], v[1], v[2], v[3]);
    q[1] = make_float4(v[4], v[5], v[6], v[7]);
}

// 3pt chamfer step: nv <- min(cur, p+1, min(neighbors)+SQ2)
__device__ __forceinline__ void step8(const float cur[8], const float p[8], float nv[8])
{
    float left  = dpp_left(p[7]);
    float right = dpp_right(p[0]);
    #pragma unroll
    for (int j = 0; j < 8; ++j) {
        float l  = (j == 0) ? left  : p[j - 1];
        float rr = (j == 7) ? right : p[j + 1];
        nv[j] = fminf(fminf(cur[j], p[j] + 1.0f), fminf(l, rr) + SQ2);
    }
}

// ---------------------------------------------------------------------------
// K1: binarize + channel max + dist init + scalar inits
// ---------------------------------------------------------------------------
__global__ __launch_bounds__(256) void k_init(const float* __restrict__ pred,
                                              const float* __restrict__ tgt,
                                              float* __restrict__ bufA,
                                              float* __restrict__ acc,
                                              unsigned* __restrict__ count,
                                              float* __restrict__ minmax)
{
    if (blockIdx.x == 0 && threadIdx.x == 0) { *acc = 0.0f; *count = 0u; }
    if (blockIdx.x == 0 && threadIdx.x < 64)
        minmax[threadIdx.x] = (threadIdx.x & 1) ? 0.0f : BIGF;

    int r = blockIdx.x & 7;
    int k = blockIdx.x >> 3;
    int b = r + 8 * (k >> 10);
    int pix = (k & 1023) * 256 + threadIdx.x;
    long base = (long)b * 3 * 262144 + pix;

    float p0 = pred[base], p1 = pred[base + 262144], p2 = pred[base + 2 * 262144];
    bool fgP = ((p0 + 1.0f) * 0.5f >= 0.7f) ||
               ((p1 + 1.0f) * 0.5f >= 0.7f) ||
               ((p2 + 1.0f) * 0.5f >= 0.7f);

    float t0 = tgt[base], t1 = tgt[base + 262144], t2 = tgt[base + 2 * 262144];
    float mt = fmaxf(fmaxf(t0, t1), t2);

    bufA[(long)b * 262144 + pix]        = fgP ? 0.0f : VF;
    bufA[(long)(16 + b) * 262144 + pix] = VF * (1.0f - mt);
}

// ---------------------------------------------------------------------------
// K_p1d: phase-1 down, PAIRED (slabs m and m+16 interleaved in one wave for
// 2x ILP on the serial chamfer chain). 256 WGs x 64. 8-deep ring each.
// ---------------------------------------------------------------------------
__global__ __launch_bounds__(64) void k_p1d(const float* __restrict__ X0,
                                            float* __restrict__ Cb)
{
    int bi = blockIdx.x, m = bi >> 4, w = bi & 15;
    const float* XA = X0 + ((long)m << 18);
    const float* XB = X0 + ((long)(m + 16) << 18);
    int c0 = (int)threadIdx.x << 3, a = w << 5;
    float pA[8], pB[8];
    load_row8(XA, a, c0, pA);
    load_row8(XB, a, c0, pB);
    float bfA[8][8], bfB[8][8];
    #pragma unroll
    for (int k = 1; k <= 7; ++k) {
        load_row8(XA, a + k, c0, bfA[k & 7]);
        load_row8(XB, a + k, c0, bfB[k & 7]);
    }
    #pragma unroll
    for (int i = 1; i < 32; ++i) {
        if (i + 7 < 32) {
            load_row8(XA, a + i + 7, c0, bfA[(i + 7) & 7]);
            load_row8(XB, a + i + 7, c0, bfB[(i + 7) & 7]);
        }
        float nvA[8], nvB[8];
        step8(bfA[i & 7], pA, nvA);
        step8(bfB[i & 7], pB, nvB);
        #pragma unroll
        for (int j = 0; j < 8; ++j) { pA[j] = nvA[j]; pB[j] = nvB[j]; }
    }
    float4* oA = (float4*)(Cb + m * 8192 + w * 512 + c0);
    oA[0] = make_float4(pA[0], pA[1], pA[2], pA[3]);
    oA[1] = make_float4(pA[4], pA[5], pA[6], pA[7]);
    float4* oB = (float4*)(Cb + (m + 16) * 8192 + w * 512 + c0);
    oB[0] = make_float4(pB[0], pB[1], pB[2], pB[3]);
    oB[1] = make_float4(pB[4], pB[5], pB[6], pB[7]);
}

// ---------------------------------------------------------------------------
// combine: bwp[wdst] = min(bwp[wdst], cone32(bwp[wsrc]))  (verified exact)
// ---------------------------------------------------------------------------
__device__ __forceinline__ void combine(float* __restrict__ bwp, float* __restrict__ part,
                                        int wdst, int wsrc, int t, int wave, int lane,
                                        const float wreg[8])
{
    const float* bs = bwp + wsrc * 576;
    if (wave <= 8) {
        int base = lane * 8 + 8 * wave;
        float W[16];
        float4 W0 = *(const float4*)(bs + base);
        float4 W1 = *(const float4*)(bs + base + 4);
        W[0]=W0.x; W[1]=W0.y; W[2]=W0.z; W[3]=W0.w;
        W[4]=W1.x; W[5]=W1.y; W[6]=W1.z; W[7]=W1.w;
        float acc[8];
        if (wave < 8) {
            float4 W2 = *(const float4*)(bs + base + 8);
            float4 W3 = *(const float4*)(bs + base + 12);
            W[8]=W2.x; W[9]=W2.y; W[10]=W2.z; W[11]=W2.w;
            W[12]=W3.x; W[13]=W3.y; W[14]=W3.z; W[15]=W3.w;
            #pragma unroll
            for (int j = 0; j < 8; ++j) acc[j] = W[j] + wreg[0];
            #pragma unroll
            for (int dt = 1; dt < 8; ++dt)
                #pragma unroll
                for (int j = 0; j < 8; ++j)
                    acc[j] = fminf(acc[j], W[j + dt] + wreg[dt]);
        } else {
            #pragma unroll
            for (int j = 0; j < 8; ++j) acc[j] = W[j] + wreg[0];
        }
        float4* pp = (float4*)(part + wave * 512 + lane * 8);
        pp[0] = make_float4(acc[0], acc[1], acc[2], acc[3]);
        pp[1] = make_float4(acc[4], acc[5], acc[6], acc[7]);
    }
    __syncthreads();
    if (t < 512) {
        float r = bwp[wdst * 576 + 32 + t];
        #pragma unroll
        for (int p2 = 0; p2 < 9; ++p2) r = fminf(r, part[p2 * 512 + t]);
        bwp[wdst * 576 + 32 + t] = r;
    }
    __syncthreads();
}

// ---------------------------------------------------------------------------
// K_comb: 15 serial combines over Cb (in place). dir=+1 down, -1 up. 32 WGs.
// ---------------------------------------------------------------------------
__global__ __launch_bounds__(1024) void k_comb(float* __restrict__ Cb, int dir)
{
    __shared__ __align__(16) float bwp[16 * 576];
    __shared__ __align__(16) float part[9 * 512];
    __shared__ float wgt[72];
    int m = blockIdx.x, t = threadIdx.x, wave = t >> 6, lane = t & 63, c0 = lane << 3;
    float* Cm = Cb + m * 8192;

    bwp[wave * 576 + ((lane < 32) ? lane : lane + 512)] = BIGF;
    *(float4*)(bwp + wave * 576 + 32 + c0)     = *(const float4*)(Cm + wave * 512 + c0);
    *(float4*)(bwp + wave * 576 + 32 + c0 + 4) = *(const float4*)(Cm + wave * 512 + c0 + 4);
    if (t < 65) { int d = t - 32; int ad = d < 0 ? -d : d; wgt[t] = ad * SQ2 + (float)(32 - ad); }
    __syncthreads();
    float wreg[8];
    #pragma unroll
    for (int dt = 0; dt < 8; ++dt) wreg[dt] = BIGF;
    if (wave < 8) {
        #pragma unroll
        for (int dt = 0; dt < 8; ++dt) wreg[dt] = wgt[wave * 8 + dt];
    } else if (wave == 8) wreg[0] = wgt[64];

    #pragma unroll 1
    for (int i = 0; i < 15; ++i) {
        int w2 = (dir > 0) ? (1 + i) : (14 - i);
        combine(bwp, part, w2, w2 - dir, t, wave, lane, wreg);
    }
    *(float4*)(Cm + wave * 512 + c0)     = *(const float4*)(bwp + wave * 576 + 32 + c0);
    *(float4*)(Cm + wave * 512 + c0 + 4) = *(const float4*)(bwp + wave * 576 + 32 + c0 + 4);
}

// ---------------------------------------------------------------------------
// K_p3d1u: seeded down (write Y) + fused phase-1 up from LDS stash. PAIRED:
// slabs m and m+16 interleaved; two 62KB stashes (124KB LDS, OK on gfx950's
// 160KB). 256 WGs x 64. Identical per-element arithmetic to the verified R1
// kernel.
// ---------------------------------------------------------------------------
__global__ __launch_bounds__(64) void k_p3d1u(const float* __restrict__ X0,
                                              float* __restrict__ Y0,
                                              const float* __restrict__ Cb,
                                              float* __restrict__ Db)
{
    __shared__ __align__(16) float stA[31 * 512];
    __shared__ __align__(16) float stB[31 * 512];
    int bi = blockIdx.x, m = bi >> 4, w = bi & 15;
    const float* XA = X0 + ((long)m << 18);
    const float* XB = X0 + ((long)(m + 16) << 18);
    float* YA = Y0 + ((long)m << 18);
    float* YB = Y0 + ((long)(m + 16) << 18);
    const int L = threadIdx.x;
    int c0 = L << 3, a = w << 5;
    float pA[8], pB[8], bfA[8][8], bfB[8][8];

    if (w == 0) {
        load_row8(XA, 0, c0, pA);
        load_row8(XB, 0, c0, pB);
        store_row8(YA, 0, c0, pA);
        store_row8(YB, 0, c0, pB);
        *(float4*)(stA + 0 * 512 + L * 4)       = make_float4(pA[0], pA[1], pA[2], pA[3]);
        *(float4*)(stA + 0 * 512 + 256 + L * 4) = make_float4(pA[4], pA[5], pA[6], pA[7]);
        *(float4*)(stB + 0 * 512 + L * 4)       = make_float4(pB[0], pB[1], pB[2], pB[3]);
        *(float4*)(stB + 0 * 512 + 256 + L * 4) = make_float4(pB[4], pB[5], pB[6], pB[7]);
        #pragma unroll
        for (int k = 1; k <= 7; ++k) {
            load_row8(XA, k, c0, bfA[k & 7]);
            load_row8(XB, k, c0, bfB[k & 7]);
        }
        #pragma unroll
        for (int i = 1; i < 32; ++i) {
            if (i + 7 < 32) {
                load_row8(XA, i + 7, c0, bfA[(i + 7) & 7]);
                load_row8(XB, i + 7, c0, bfB[(i + 7) & 7]);
            }
            float nvA[8], nvB[8];
            step8(bfA[i & 7], pA, nvA);
            step8(bfB[i & 7], pB, nvB);
            store_row8(YA, i, c0, nvA);
            store_row8(YB, i, c0, nvB);
            if (i < 31) {
                *(float4*)(stA + i * 512 + L * 4)       = make_float4(nvA[0], nvA[1], nvA[2], nvA[3]);
                *(float4*)(stA + i * 512 + 256 + L * 4) = make_float4(nvA[4], nvA[5], nvA[6], nvA[7]);
                *(float4*)(stB + i * 512 + L * 4)       = make_float4(nvB[0], nvB[1], nvB[2], nvB[3]);
                *(float4*)(stB + i * 512 + 256 + L * 4) = make_float4(nvB[4], nvB[5], nvB[6], nvB[7]);
            }
            #pragma unroll
            for (int j = 0; j < 8; ++j) { pA[j] = nvA[j]; pB[j] = nvB[j]; }
        }
    } else {
        {
            const float4* sA = (const float4*)(Cb + m * 8192 + (w - 1) * 512 + c0);
            float4 s0 = sA[0], s1 = sA[1];
            pA[0]=s0.x; pA[1]=s0.y; pA[2]=s0.z; pA[3]=s0.w;
            pA[4]=s1.x; pA[5]=s1.y; pA[6]=s1.z; pA[7]=s1.w;
            const float4* sB = (const float4*)(Cb + (m + 16) * 8192 + (w - 1) * 512 + c0);
            float4 t0 = sB[0], t1 = sB[1];
            pB[0]=t0.x; pB[1]=t0.y; pB[2]=t0.z; pB[3]=t0.w;
            pB[4]=t1.x; pB[5]=t1.y; pB[6]=t1.z; pB[7]=t1.w;
        }
        #pragma unroll
        for (int k = 0; k < 7; ++k) {
            load_row8(XA, a + k, c0, bfA[k & 7]);
            load_row8(XB, a + k, c0, bfB[k & 7]);
        }
        #pragma unroll
        for (int i = 0; i < 32; ++i) {
            if (i + 7 < 32) {
                load_row8(XA, a + i + 7, c0, bfA[(i + 7) & 7]);
                load_row8(XB, a + i + 7, c0, bfB[(i + 7) & 7]);
            }
            float nvA[8], nvB[8];
            step8(bfA[i & 7], pA, nvA);
            step8(bfB[i & 7], pB, nvB);
            store_row8(YA, a + i, c0, nvA);
            store_row8(YB, a + i, c0, nvB);
            if (i < 31) {
                *(float4*)(stA + i * 512 + L * 4)       = make_float4(nvA[0], nvA[1], nvA[2], nvA[3]);
                *(float4*)(stA + i * 512 + 256 + L * 4) = make_float4(nvA[4], nvA[5], nvA[6], nvA[7]);
                *(float4*)(stB + i * 512 + L * 4)       = make_float4(nvB[0], nvB[1], nvB[2], nvB[3]);
                *(float4*)(stB + i * 512 + 256 + L * 4) = make_float4(nvB[4], nvB[5], nvB[6], nvB[7]);
            }
            #pragma unroll
            for (int j = 0; j < 8; ++j) { pA[j] = nvA[j]; pB[j] = nvB[j]; }
        }
    }

    // fused phase-1 up from stash; seed = row a+31 (in pA/pB)
    float qA[8], qB[8], curA[8], curB[8];
    #pragma unroll
    for (int j = 0; j < 8; ++j) { qA[j] = pA[j]; qB[j] = pB[j]; }
    {
        float4 x0 = *(const float4*)(stA + 30 * 512 + L * 4);
        float4 x1 = *(const float4*)(stA + 30 * 512 + 256 + L * 4);
        curA[0]=x0.x; curA[1]=x0.y; curA[2]=x0.z; curA[3]=x0.w;
        curA[4]=x1.x; curA[5]=x1.y; curA[6]=x1.z; curA[7]=x1.w;
        float4 y0 = *(const float4*)(stB + 30 * 512 + L * 4);
        float4 y1 = *(const float4*)(stB + 30 * 512 + 256 + L * 4);
        curB[0]=y0.x; curB[1]=y0.y; curB[2]=y0.z; curB[3]=y0.w;
        curB[4]=y1.x; curB[5]=y1.y; curB[6]=y1.z; curB[7]=y1.w;
    }
    #pragma unroll
    for (int i = 1; i < 32; ++i) {
        float nxA[8], nxB[8];
        if (i < 31) {
            float4 x0 = *(const float4*)(stA + (30 - i) * 512 + L * 4);
            float4 x1 = *(const float4*)(stA + (30 - i) * 512 + 256 + L * 4);
            nxA[0]=x0.x; nxA[1]=x0.y; nxA[2]=x0.z; nxA[3]=x0.w;
            nxA[4]=x1.x; nxA[5]=x1.y; nxA[6]=x1.z; nxA[7]=x1.w;
            float4 y0 = *(const float4*)(stB + (30 - i) * 512 + L * 4);
            float4 y1 = *(const float4*)(stB + (30 - i) * 512 + 256 + L * 4);
            nxB[0]=y0.x; nxB[1]=y0.y; nxB[2]=y0.z; nxB[3]=y0.w;
            nxB[4]=y1.x; nxB[5]=y1.y; nxB[6]=y1.z; nxB[7]=y1.w;
        }
        float nvA[8], nvB[8];
        step8(curA, qA, nvA);
        step8(curB, qB, nvB);
        #pragma unroll
        for (int j = 0; j < 8; ++j) { qA[j] = nvA[j]; qB[j] = nvB[j]; }
        if (i < 31) {
            #pragma unroll
            for (int j = 0; j < 8; ++j) { curA[j] = nxA[j]; curB[j] = nxB[j]; }
        }
    }
    float4* oA = (float4*)(Db + m * 8192 + w * 512 + c0);
    oA[0] = make_float4(qA[0], qA[1], qA[2], qA[3]);
    oA[1] = make_float4(qA[4], qA[5], qA[6], qA[7]);
    float4* oB = (float4*)(Db + (m + 16) * 8192 + w * 512 + c0);
    oB[0] = make_float4(qB[0], qB[1], qB[2], qB[3]);
    oB[1] = make_float4(qB[4], qB[5], qB[6], qB[7]);
}

// ---------------------------------------------------------------------------
// K_p3u: phase-3 up + fused TRANSPOSED write + minmax. PAIRED (two 33KB
// tiles = 66KB LDS). 256 WGs x 64. Identical arithmetic to verified R1.
// ---------------------------------------------------------------------------
__device__ __forceinline__ void tile_store(float* tile, int h, int c0, const float v[8])
{
    float4* q = (float4*)(tile + h * 516 + c0);
    q[0] = make_float4(v[0], v[1], v[2], v[3]);
    q[1] = make_float4(v[4], v[5], v[6], v[7]);
}
__device__ __forceinline__ void half_out(const float* tile, float* __restrict__ Xo,
                                         int a2, int L)
{
    int g = L >> 2, j = (L & 3) << 2;
    #pragma unroll
    for (int it = 0; it < 32; ++it) {
        int c = (it << 4) + g;
        float4 v = make_float4(tile[(j + 0) * 516 + c], tile[(j + 1) * 516 + c],
                               tile[(j + 2) * 516 + c], tile[(j + 3) * 516 + c]);
        *(float4*)(Xo + (long)c * 512 + a2 + j) = v;
    }
}

__global__ __launch_bounds__(64) void k_p3u(const float* __restrict__ Y0,
                                            float* __restrict__ Xo0,
                                            const float* __restrict__ Db,
                                            float* __restrict__ minmax,
                                            int final_pass)
{
    __shared__ __align__(16) float tA[16 * 516];
    __shared__ __align__(16) float tB[16 * 516];
    int bi = blockIdx.x, m = bi >> 4, w = bi & 15;
    const float* YA = Y0 + ((long)m << 18);
    const float* YB = Y0 + ((long)(m + 16) << 18);
    float* XoA = Xo0 + ((long)m << 18);
    float* XoB = Xo0 + ((long)(m + 16) << 18);
    int L = threadIdx.x, c0 = L << 3, a = w << 5;
    float pA[8], pB[8], bfA[8][8], bfB[8][8];
    float mnA = BIGF, mxA = -BIGF, mnB = BIGF, mxB = -BIGF;

    if (w == 15) {
        load_row8(YA, 511, c0, pA);
        load_row8(YB, 511, c0, pB);
        tile_store(tA, 15, c0, pA);
        tile_store(tB, 15, c0, pB);
        #pragma unroll
        for (int j = 0; j < 8; ++j) {
            mnA = fminf(mnA, pA[j]); mxA = fmaxf(mxA, pA[j]);
            mnB = fminf(mnB, pB[j]); mxB = fmaxf(mxB, pB[j]);
        }
        #pragma unroll
        for (int k = 1; k <= 7; ++k) {
            load_row8(YA, 511 - k, c0, bfA[k & 7]);
            load_row8(YB, 511 - k, c0, bfB[k & 7]);
        }
        #pragma unroll
        for (int i = 1; i < 16; ++i) {
            load_row8(YA, 511 - (i + 7), c0, bfA[(i + 7) & 7]);
            load_row8(YB, 511 - (i + 7), c0, bfB[(i + 7) & 7]);
            float nvA[8], nvB[8];
            step8(bfA[i & 7], pA, nvA);
            step8(bfB[i & 7], pB, nvB);
            tile_store(tA, 15 - i, c0, nvA);
            tile_store(tB, 15 - i, c0, nvB);
            #pragma unroll
            for (int j = 0; j < 8; ++j) {
                pA[j] = nvA[j]; mnA = fminf(mnA, nvA[j]); mxA = fmaxf(mxA, nvA[j]);
                pB[j] = nvB[j]; mnB = fminf(mnB, nvB[j]); mxB = fmaxf(mxB, nvB[j]);
            }
        }
        half_out(tA, XoA, a + 16, L);
        half_out(tB, XoB, a + 16, L);
        #pragma unroll
        for (int i = 16; i < 32; ++i) {
            if (i + 7 < 32) {
                load_row8(YA, 511 - (i + 7), c0, bfA[(i + 7) & 7]);
                load_row8(YB, 511 - (i + 7), c0, bfB[(i + 7) & 7]);
            }
            float nvA[8], nvB[8];
            step8(bfA[i & 7], pA, nvA);
            step8(bfB[i & 7], pB, nvB);
            tile_store(tA, 31 - i, c0, nvA);
            tile_store(tB, 31 - i, c0, nvB);
            #pragma unroll
            for (int j = 0; j < 8; ++j) {
                pA[j] = nvA[j]; mnA = fminf(mnA, nvA[j]); mxA = fmaxf(mxA, nvA[j]);
                pB[j] = nvB[j]; mnB = fminf(mnB, nvB[j]); mxB = fmaxf(mxB, nvB[j]);
            }
        }
        half_out(tA, XoA, a, L);
        half_out(tB, XoB, a, L);
    } else {
        {
            const float4* sA = (const float4*)(Db + m * 8192 + (w + 1) * 512 + c0);
            float4 s0 = sA[0], s1 = sA[1];
            pA[0]=s0.x; pA[1]=s0.y; pA[2]=s0.z; pA[3]=s0.w;
            pA[4]=s1.x; pA[5]=s1.y; pA[6]=s1.z; pA[7]=s1.w;
            const float4* sB = (const float4*)(Db + (m + 16) * 8192 + (w + 1) * 512 + c0);
            float4 t0 = sB[0], t1 = sB[1];
            pB[0]=t0.x; pB[1]=t0.y; pB[2]=t0.z; pB[3]=t0.w;
            pB[4]=t1.x; pB[5]=t1.y; pB[6]=t1.z; pB[7]=t1.w;
        }
        #pragma unroll
        for (int k = 0; k < 7; ++k) {
            load_row8(YA, a + 31 - k, c0, bfA[k & 7]);
            load_row8(YB, a + 31 - k, c0, bfB[k & 7]);
        }
        #pragma unroll
        for (int i = 0; i < 16; ++i) {
            {
                load_row8(YA, a + 31 - (i + 7), c0, bfA[(i + 7) & 7]);
                load_row8(YB, a + 31 - (i + 7), c0, bfB[(i + 7) & 7]);
            }
            float nvA[8], nvB[8];
            step8(bfA[i & 7], pA, nvA);
            step8(bfB[i & 7], pB, nvB);
            tile_store(tA, 15 - i, c0, nvA);
            tile_store(tB, 15 - i, c0, nvB);
            #pragma unroll
            for (int j = 0; j < 8; ++j) {
                pA[j] = nvA[j]; mnA = fminf(mnA, nvA[j]); mxA = fmaxf(mxA, nvA[j]);
                pB[j] = nvB[j]; mnB = fminf(mnB, nvB[j]); mxB = fmaxf(mxB, nvB[j]);
            }
        }
        half_out(tA, XoA, a + 16, L);
        half_out(tB, XoB, a + 16, L);
        #pragma unroll
        for (int i = 16; i < 32; ++i) {
            if (i + 7 < 32) {
                load_row8(YA, a + 31 - (i + 7), c0, bfA[(i + 7) & 7]);
                load_row8(YB, a + 31 - (i + 7), c0, bfB[(i + 7) & 7]);
            }
            float nvA[8], nvB[8];
            step8(bfA[i & 7], pA, nvA);
            step8(bfB[i & 7], pB, nvB);
            tile_store(tA, 31 - i, c0, nvA);
            tile_store(tB, 31 - i, c0, nvB);
            #pragma unroll
            for (int j = 0; j < 8; ++j) {
                pA[j] = nvA[j]; mnA = fminf(mnA, nvA[j]); mxA = fmaxf(mxA, nvA[j]);
                pB[j] = nvB[j]; mnB = fminf(mnB, nvB[j]); mxB = fmaxf(mxB, nvB[j]);
            }
        }
        half_out(tA, XoA, a, L);
        half_out(tB, XoB, a, L);
    }

    if (final_pass) {
        for (int o = 32; o > 0; o >>= 1) {
            mnA = fminf(mnA, __shfl_down(mnA, o));
            mxA = fmaxf(mxA, __shfl_down(mxA, o));
            mnB = fminf(mnB, __shfl_down(mnB, o));
            mxB = fmaxf(mxB, __shfl_down(mxB, o));
        }
        if (L == 0) {
            atomicMin((int*)(minmax + 2 * m),     __float_as_int(mnA));
            atomicMax((int*)(minmax + 2 * m + 1), __float_as_int(mxA));
            atomicMin((int*)(minmax + 2 * (m + 16)),     __float_as_int(mnB));
            atomicMax((int*)(minmax + 2 * (m + 16) + 1), __float_as_int(mxB));
        }
    }
}

// ---------------------------------------------------------------------------
// K_loss: NORMALIZED bitonic sort (all comparators min-low) with med3 trick.
// lstage LDS slots XOR-half-swizzled (verified: conflicts 2.36M -> 786K).
// ---------------------------------------------------------------------------
__device__ __forceinline__ void cex(float& lo, float& hi)
{
    float l = fminf(lo, hi);
    hi = fmaxf(lo, hi);
    lo = l;
}
__device__ __forceinline__ void merge8asc(float v[8])
{
    cex(v[0],v[4]); cex(v[1],v[5]); cex(v[2],v[6]); cex(v[3],v[7]);
    cex(v[0],v[2]); cex(v[1],v[3]); cex(v[4],v[6]); cex(v[5],v[7]);
    cex(v[0],v[1]); cex(v[2],v[3]); cex(v[4],v[5]); cex(v[6],v[7]);
}
__device__ __forceinline__ void sort8asc(float v[8])
{
    cex(v[0],v[1]); cex(v[2],v[3]); cex(v[4],v[5]); cex(v[6],v[7]);   // k=2
    cex(v[0],v[3]); cex(v[1],v[2]); cex(v[4],v[7]); cex(v[5],v[6]);   // k=4 rev
    cex(v[0],v[1]); cex(v[2],v[3]); cex(v[4],v[5]); cex(v[6],v[7]);   // k=4 j=1
    cex(v[0],v[7]); cex(v[1],v[6]); cex(v[2],v[5]); cex(v[3],v[4]);   // k=8 rev
    cex(v[0],v[2]); cex(v[1],v[3]); cex(v[4],v[6]); cex(v[5],v[7]);   // j=2
    cex(v[0],v[1]); cex(v[2],v[3]); cex(v[4],v[5]); cex(v[6],v[7]);   // j=1
}
__device__ __forceinline__ void xshfl(float v[8], int j8, float sel)
{
    #pragma unroll
    for (int e = 0; e < 8; ++e) {
        float o = __shfl_xor(v[e], j8);
        v[e] = fmed3(v[e], o, sel);
    }
}
template<int CTRL>
__device__ __forceinline__ void xdpp(float v[8], float sel)
{
    #pragma unroll
    for (int e = 0; e < 8; ++e) {
        float o = qdpp<CTRL>(v[e]);
        v[e] = fmed3(v[e], o, sel);
    }
}
__device__ __forceinline__ void rshfl(float v[8], int tmask, float sel)
{
    float o[8];
    #pragma unroll
    for (int e = 0; e < 8; ++e) o[e] = __shfl_xor(v[7 - e], tmask);
    #pragma unroll
    for (int e = 0; e < 8; ++e) v[e] = fmed3(v[e], o[e], sel);
}
template<int CTRL>
__device__ __forceinline__ void rdpp(float v[8], float sel)
{
    float o[8];
    #pragma unroll
    for (int e = 0; e < 8; ++e) o[e] = qdpp<CTRL>(v[7 - e]);
    #pragma unroll
    for (int e = 0; e < 8; ++e) v[e] = fmed3(v[e], o[e], sel);
}
__device__ __forceinline__ void lstage(float p[8], float q[8], int tmask, float sel, bool rev,
                                       float* sp, float* st, int t)
{
    __syncthreads();
    int sw = (t >> 2) & 1;                 // half-swap swizzle bit
    int o0 = t * 8 + sw * 4;
    int o1 = t * 8 + (sw ^ 1) * 4;
    *(float4*)(sp + o0) = make_float4(p[0], p[1], p[2], p[3]);
    *(float4*)(sp + o1) = make_float4(p[4], p[5], p[6], p[7]);
    *(float4*)(st + o0) = make_float4(q[0], q[1], q[2], q[3]);
    *(float4*)(st + o1) = make_float4(q[4], q[5], q[6], q[7]);
    __syncthreads();
    int pt = t ^ tmask;
    int psw = (pt >> 2) & 1;
    int q0 = pt * 8 + psw * 4;
    int q1 = pt * 8 + (psw ^ 1) * 4;
    float4 a = *(const float4*)(sp + q0), bb = *(const float4*)(sp + q1);
    float4 c = *(const float4*)(st + q0), d = *(const float4*)(st + q1);
    float op[8] = {a.x,a.y,a.z,a.w,bb.x,bb.y,bb.z,bb.w};
    float oq[8] = {c.x,c.y,c.z,c.w,d.x,d.y,d.z,d.w};
    if (rev) {
        #pragma unroll
        for (int e = 0; e < 8; ++e) {
            p[e] = fmed3(p[e], op[7 - e], sel);
            q[e] = fmed3(q[e], oq[7 - e], sel);
        }
    } else {
        #pragma unroll
        for (int e = 0; e < 8; ++e) {
            p[e] = fmed3(p[e], op[e], sel);
            q[e] = fmed3(q[e], oq[e], sel);
        }
    }
}

__global__ __launch_bounds__(512) void k_loss(const float* __restrict__ bufB,
                                              const float* __restrict__ minmax,
                                              float* __restrict__ acc,
                                              unsigned* __restrict__ count,
                                              float* __restrict__ out)
{
    __shared__ float sp[4096];
    __shared__ float st[4096];
    __shared__ float rs[8];

    int t = threadIdx.x;
    int r = blockIdx.x & 7;
    int k = blockIdx.x >> 3;
    int b = r + 8 * (k >> 6);
    int w = k & 63;
    int wi = w >> 3, wj = w & 7;

    int i0 = t << 3;
    int y = wi * 64 + (i0 >> 6);
    int x = wj * 64 + (i0 & 63);

    float mnP = minmax[2 * b],        mxP = minmax[2 * b + 1];
    float mnT = minmax[2 * (16 + b)], mxT = minmax[2 * (16 + b) + 1];
    float sclP = 1.0f / (mxP - mnP + 1e-6f);
    float sclT = 1.0f / (mxT - mnT + 1e-6f);

    float p[8], q[8];
    {
        const float4* P4 = (const float4*)(bufB + (long)b * 262144 + y * 512 + x);
        const float4* T4 = (const float4*)(bufB + (long)(16 + b) * 262144 + y * 512 + x);
        float4 a = P4[0], bb = P4[1], c = T4[0], d = T4[1];
        p[0]=a.x; p[1]=a.y; p[2]=a.z; p[3]=a.w; p[4]=bb.x; p[5]=bb.y; p[6]=bb.z; p[7]=bb.w;
        q[0]=c.x; q[1]=c.y; q[2]=c.z; q[3]=c.w; q[4]=d.x;  q[5]=d.y;  q[6]=d.z;  q[7]=d.w;
        #pragma unroll
        for (int e = 0; e < 8; ++e) {
            p[e] = (p[e] - mnP) * sclP;
            q[e] = (q[e] - mnT) * sclT;
        }
    }

    const float INFP = __builtin_inff();
    sort8asc(p); sort8asc(q);

    #pragma unroll 1
    for (int kk = 16; kk <= 4096; kk <<= 1) {
        int tmask = (kk - 1) >> 3;
        float sel = ((t & (kk >> 4)) == 0) ? -INFP : INFP;
        if (kk == 16)        { rdpp<0xB1>(p, sel); rdpp<0xB1>(q, sel); }
        else if (kk == 32)   { rdpp<0x1B>(p, sel); rdpp<0x1B>(q, sel); }
        else if (tmask < 64) { rshfl(p, tmask, sel); rshfl(q, tmask, sel); }
        else                 lstage(p, q, tmask, sel, true, sp, st, t);

        #pragma unroll 1
        for (int j = kk >> 2; j >= 8; j >>= 1) {
            int j8 = j >> 3;
            float s2 = ((t & j8) == 0) ? -INFP : INFP;
            if (j8 == 1)      { xdpp<0xB1>(p, s2); xdpp<0xB1>(q, s2); }
            else if (j8 == 2) { xdpp<0x4E>(p, s2); xdpp<0x4E>(q, s2); }
            else if (j8 < 64) { xshfl(p, j8, s2); xshfl(q, j8, s2); }
            else              lstage(p, q, j8, s2, false, sp, st, t);
        }
        merge8asc(p); merge8asc(q);
    }

    float s = 0.0f;
    #pragma unroll
    for (int e = 0; e < 8; ++e) { float d = p[e] - q[e]; s += d * d; }
    for (int o = 32; o > 0; o >>= 1) s += __shfl_down(s, o);
    if ((t & 63) == 0) rs[t >> 6] = s;
    __syncthreads();
    if (t == 0) {
        float tot = 0.0f;
        #pragma unroll
        for (int i = 0; i < 8; ++i) tot += rs[i];
        atomicAdd(acc, tot);
        __threadfence();
        unsigned done = atomicAdd(count, 1u);
        if (done == 1023u) {
            float total = atomicAdd(acc, 0.0f);
            float mean = total * (1.0f / 4194304.0f);
            out[0] = mean * 0.005f;
            out[1] = mean;
        }
    }
}

extern "C" void kernel_launch(void* const* d_in, const int* in_sizes, int n_in,
                              void* d_out, int out_size, void* d_ws, size_t ws_size,
                              hipStream_t stream)
{
    const float* pred = (const float*)d_in[0];
    const float* tgt  = (const float*)d_in[1];
    float* out = (float*)d_out;

    char* ws = (char*)d_ws;
    float* bufA     = (float*)ws;                       // 32 MB
    float* bufB     = (float*)(ws + (32ull << 20));     // 32 MB (Y intermediate)
    float* Cb       = (float*)(ws + (64ull << 20));     // 1 MB boundary rows (down)
    float* Db       = (float*)(ws + (65ull << 20));     // 1 MB boundary rows (up)
    float* minmax   = (float*)(ws + (66ull << 20));     // 64 floats
    float* acc      = minmax + 64;
    unsigned* count = (unsigned*)(acc + 1);

    k_init<<<16 * 1024, 256, 0, stream>>>(pred, tgt, bufA, acc, count, minmax);

    for (int s = 0; s < 4; ++s) {
        k_p1d  <<<256,   64, 0, stream>>>(bufA, Cb);
        k_comb <<< 32, 1024, 0, stream>>>(Cb, +1);
        k_p3d1u<<<256,   64, 0, stream>>>(bufA, bufB, Cb, Db);
        k_comb <<< 32, 1024, 0, stream>>>(Db, -1);
        k_p3u  <<<256,   64, 0, stream>>>(bufB, bufA, Db, minmax, s == 3 ? 1 : 0);
    }

    k_loss<<<1024, 512, 0, stream>>>(bufA, minmax, acc, count, out);
}